// Round 5
// baseline (104.883 us; speedup 1.0000x reference)
//
#include <hip/hip_runtime.h>

// z[b,c,m] = sum_d S[m,c,d] * (x[b,d,m] - mean[d,m])
// B=1024, C=64, M=512. x:(B,C,M) f32, mean:(1,C,M), S:(M,C,C), out f32.
//
// Per m: Z_m(64c x b) = S_m(64x64) @ Xc_m(64d x b), mfma_f32_16x16x32_bf16.
// Block: 512 thr (8 waves), tile 16 m x 16 b; wave w owns m_loc {2w, 2w+1}.
// LDS 32 KB static: x-tile bf16 [row=m*16+b][d], then reused for z transpose.

typedef __attribute__((ext_vector_type(8))) short short8;
typedef __attribute__((ext_vector_type(4))) float f32x4;

namespace {
constexpr int Mm = 512, Cc = 64, Bb = 1024;
constexpr int MT = 16;  // m per block
constexpr int BT = 16;  // b per block
constexpr int ZR = 20;  // z row pitch (floats): 16B-aligned, bank-spread

__device__ __forceinline__ unsigned short f2bf(float x) {  // RNE f32->bf16
  unsigned u = __float_as_uint(x);
  u = (u + 0x7fffu + ((u >> 16) & 1u)) >> 16;
  return (unsigned short)u;
}
// x-LDS chunk swizzle: ^(row&7) spreads reads (row = m*16 + lane&15),
// ^((row>>6)&3)<<1 spreads writes (simultaneous writes differ only in mq=row>>6).
__device__ __forceinline__ int xsw(int row, int chunk) {
  return chunk ^ (row & 7) ^ (((row >> 6) & 3) << 1);
}
}  // namespace

__global__ __launch_bounds__(512, 6) void zca_mfma(
    const float* __restrict__ x, const float* __restrict__ mean,
    const float* __restrict__ S, float* __restrict__ out) {
  __shared__ char lds_raw[32768];  // x: 256 rows * 64 bf16 = 32768 B; z: 20480 B
  unsigned short* xl = (unsigned short*)lds_raw;
  float* zl = (float*)lds_raw;

  const int tid = threadIdx.x;
  const int lane = tid & 63;
  const int w = __builtin_amdgcn_readfirstlane(tid >> 6);  // 0..7

  // bijective XCD swizzle: 2048 blocks -> each XCD a contiguous sw range
  const int id = blockIdx.x;
  const int sw = ((id & 7) << 8) + (id >> 3);
  const int m0 = (sw >> 6) * MT;  // 32 m-tiles
  const int b0 = (sw & 63) * BT;  // 64 b-tiles

  const int mq = tid & 3;   // float4 index along m
  const int rs = tid >> 2;  // 0..127
  const int d = rs & 63;
  const int bg = rs >> 6;  // 0..1

  // ---- stage (x - mean) -> bf16 LDS, conflict-free swizzled ----
  const float4 mv = *(const float4*)(mean + (size_t)d * Mm + m0 + mq * 4);
  float4 xv[8];
#pragma unroll
  for (int p = 0; p < 8; ++p) {
    const int b = p * 2 + bg;
    xv[p] = *(const float4*)(x + (size_t)((b0 + b) * Cc + d) * Mm + m0 + mq * 4);
  }
#pragma unroll
  for (int p = 0; p < 8; ++p) {
    const int b = p * 2 + bg;
    const float v[4] = {xv[p].x - mv.x, xv[p].y - mv.y, xv[p].z - mv.z,
                        xv[p].w - mv.w};
#pragma unroll
    for (int i = 0; i < 4; ++i) {
      const int row = (mq * 4 + i) * BT + b;  // m_loc*16 + b
      xl[row * 64 + (xsw(row, d >> 3) << 3) + (d & 7)] = f2bf(v[i]);
    }
  }
  __syncthreads();

  // ---- B fragments: 2 m x 2 ks per wave ----
  short8 Bf[2][2];
#pragma unroll
  for (int mi = 0; mi < 2; ++mi) {
    const int row = (w * 2 + mi) * BT + (lane & 15);
#pragma unroll
    for (int ks = 0; ks < 2; ++ks)
      Bf[mi][ks] =
          *(const short8*)(xl + row * 64 + (xsw(row, ks * 4 + (lane >> 4)) << 3));
  }
  __syncthreads();  // all x reads done; zl may be overwritten after MFMAs

  // ---- A fragments from S (L2-resident per XCD) + 16 MFMAs ----
  f32x4 acc[2][4];
#pragma unroll
  for (int mi = 0; mi < 2; ++mi)
#pragma unroll
    for (int ct = 0; ct < 4; ++ct) acc[mi][ct] = (f32x4){0.f, 0.f, 0.f, 0.f};

#pragma unroll
  for (int mi = 0; mi < 2; ++mi) {
    const int m = m0 + w * 2 + mi;
#pragma unroll
    for (int ks = 0; ks < 2; ++ks) {
#pragma unroll
      for (int ct = 0; ct < 4; ++ct) {
        const float* sp = S + ((size_t)m * Cc + ct * 16 + (lane & 15)) * Cc +
                          ks * 32 + (lane >> 4) * 8;
        const float4 f0 = *(const float4*)sp;
        const float4 f1 = *(const float4*)(sp + 4);
        short8 a;
        a[0] = (short)f2bf(f0.x); a[1] = (short)f2bf(f0.y);
        a[2] = (short)f2bf(f0.z); a[3] = (short)f2bf(f0.w);
        a[4] = (short)f2bf(f1.x); a[5] = (short)f2bf(f1.y);
        a[6] = (short)f2bf(f1.z); a[7] = (short)f2bf(f1.w);
        acc[mi][ct] = __builtin_amdgcn_mfma_f32_16x16x32_bf16(
            a, Bf[mi][ks], acc[mi][ct], 0, 0, 0);
      }
    }
  }

  // ---- epilogue: 4 c-group transposes through zl (compile-time CT) ----
  // D layout: lane holds D[(lane>>4)*4 + r][lane&15] = Z[c][b].
#define EPI(CT, LAST)                                                         \
  {                                                                           \
    _Pragma("unroll") for (int mi = 0; mi < 2; ++mi) {                        \
      const int m = w * 2 + mi;                                               \
      _Pragma("unroll") for (int r = 0; r < 4; ++r) {                         \
        const int row = ((lane >> 4) * 4 + r) * 16 + (lane & 15);             \
        const int col = ((((m >> 2) ^ ((row >> 6) & 3))) << 2) + (m & 3);     \
        zl[row * ZR + col] = acc[mi][CT][r];                                  \
      }                                                                       \
    }                                                                         \
    __syncthreads();                                                          \
    _Pragma("unroll") for (int t = 0; t < 2; ++t) {                           \
      const int row = t * 128 + rs; /* cl*16 + b */                           \
      const int qd = mq ^ ((row >> 6) & 3);                                   \
      const float4 v = *(const float4*)(zl + row * ZR + qd * 4);              \
      const int b = row & 15, cl = row >> 4;                                  \
      *(float4*)(out + (size_t)(((b0 + b) * Cc + (CT)*16 + cl) * Mm) + m0 +   \
                 mq * 4) = v;                                                 \
    }                                                                         \
    if (!(LAST)) __syncthreads();                                             \
  }
  EPI(0, 0)
  EPI(1, 0)
  EPI(2, 0)
  EPI(3, 1)
#undef EPI
}

extern "C" void kernel_launch(void* const* d_in, const int* in_sizes, int n_in,
                              void* d_out, int out_size, void* d_ws,
                              size_t ws_size, hipStream_t stream) {
  const float* x = (const float*)d_in[0];
  const float* mean = (const float*)d_in[1];
  const float* S = (const float*)d_in[2];
  float* out = (float*)d_out;
  const int nblocks = (Mm / MT) * (Bb / BT);  // 32 * 64 = 2048
  hipLaunchKernelGGL(zca_mfma, dim3(nblocks), dim3(512), 0, stream, x, mean, S,
                     out);
}

// Round 6
// 74.933 us; speedup vs baseline: 1.3997x; 1.3997x over previous
//
#include <hip/hip_runtime.h>

// z[b,c,m] = sum_d S[m,c,d] * (x[b,d,m] - mean[d,m])
// B=1024, C=64, M=512. x:(B,C,M) f32, mean:(1,C,M), S:(M,C,C), out f32.
//
// v6: persistent b-loop. 256 blocks (1/CU), 16 waves, 1 m per wave.
// S[m] -> bf16 A-fragments in registers ONCE per block; loop over 8 b-subtiles
// of 16 with double-buffered bf16 x staging in LDS. Raw s_barrier + lgkmcnt(0)
// only (no vmcnt drain) so prefetch loads stay in flight across barriers (T14).

typedef __attribute__((ext_vector_type(8))) short short8;
typedef __attribute__((ext_vector_type(4))) float f32x4;

namespace {
constexpr int Mm = 512, Cc = 64, Bb = 1024;
constexpr int MT = 16;  // m per block (1 per wave)
constexpr int BT = 16;  // b per iteration
constexpr int NB = 8;   // b-subtiles per block
constexpr int ZR = 20;  // z transpose row pitch (floats)
constexpr size_t LDSB = 2 * 32768 + 1024 * ZR * 4;  // 147456 B

__device__ __forceinline__ unsigned short f2bf(float v) {  // RNE f32->bf16
  unsigned uu = __float_as_uint(v);
  uu = (uu + 0x7fffu + ((uu >> 16) & 1u)) >> 16;
  return (unsigned short)uu;
}
__device__ __forceinline__ unsigned pack2(float a, float b) {
  return (unsigned)f2bf(a) | ((unsigned)f2bf(b) << 16);
}
// x-LDS chunk swizzle: ^(row&7) spreads b128 reads (rows = l&15),
// ^((row>>6)&3)<<1 spreads b32 writes (simultaneous writes vary row via mq).
__device__ __forceinline__ int xsw(int row, int chunk) {
  return chunk ^ (row & 7) ^ (((row >> 6) & 3) << 1);
}
}  // namespace

#define ELEM(V, I) \
  ((I) == 0 ? (V).x : (I) == 1 ? (V).y : (I) == 2 ? (V).z : (V).w)

__global__ __launch_bounds__(1024, 4) void zca_pipe(
    const float* __restrict__ x, const float* __restrict__ mean,
    const float* __restrict__ S, float* __restrict__ out) {
  extern __shared__ unsigned char lds[];
  unsigned char* xbuf0 = lds;            // 32 KB bf16 x tile, buffer 0
  unsigned char* xbuf1 = lds + 32768;    // 32 KB buffer 1
  float* zl = (float*)(lds + 65536);     // 80 KB z transpose

  const int tid = threadIdx.x;
  const int l = tid & 63;
  const int w = __builtin_amdgcn_readfirstlane(tid >> 6);  // wave = m_local

  // bijective XCD swizzle: 256 blocks -> 4 m-tiles x 8 b-groups per XCD
  const int id = blockIdx.x;
  const int sw = ((id & 7) << 5) + (id >> 3);
  const int m0 = (sw >> 3) * MT;
  const int bg = (sw & 7) * (BT * NB);

  // staging mapping: thread covers (d2,d2+1) x (b: p*8+bq) x (m: mq*4..+3)
  const int mq = tid & 3;
  const int u = (tid >> 2) & 15;
  const int d2 = ((w & 1) << 5) + (u << 1);
  const int bq = w >> 1;
  const int chunkS = ((w & 1) << 2) + (u >> 2);  // d2 >> 3
  const int rowB = (w << 4) + (l & 15);          // B-frag LDS row
  const int rs = tid >> 2;                       // 0..255

  float4 st0[4], st1[4];

#define ISSUE(ST, T)                                                          \
  {                                                                           \
    _Pragma("unroll") for (int dd = 0; dd < 2; ++dd)                          \
        _Pragma("unroll") for (int p = 0; p < 2; ++p)                         \
            ST[dd * 2 + p] = *(const float4*)(                                \
                x + (size_t)((bg + (T)*BT + p * 8 + bq) * Cc + d2 + dd) * Mm  \
                  + m0 + mq * 4);                                             \
  }

#define STAGE(ST, XW)                                                         \
  {                                                                           \
    _Pragma("unroll") for (int p = 0; p < 2; ++p) {                           \
      _Pragma("unroll") for (int i = 0; i < 4; ++i) {                         \
        const int row = (mq * 4 + i) * BT + p * 8 + bq;                       \
        const unsigned v = pack2(ELEM(ST[p], i) - ELEM(mv0, i),               \
                                 ELEM(ST[2 + p], i) - ELEM(mv1, i));          \
        *(unsigned*)((XW) + row * 128 + xsw(row, chunkS) * 16 + (u & 3) * 4) = \
            v;                                                                \
      }                                                                       \
    }                                                                         \
  }

#define BAR()                                           \
  {                                                     \
    asm volatile("s_waitcnt lgkmcnt(0)" ::: "memory");  \
    __builtin_amdgcn_s_barrier();                       \
  }

#define ZW(CT, R, AC)                                                   \
  {                                                                     \
    const int c_ = (CT)*16 + (l >> 4) * 4 + (R);                        \
    const int zrow = c_ * 16 + (l & 15);                                \
    const int col = (((w >> 2) ^ ((zrow >> 6) & 3)) << 2) + (w & 3);    \
    zl[zrow * ZR + col] = (AC)[(R)];                                    \
  }

  // ---- prologue: issue tiles 0,1; load mean; load+cvt S frags; stage 0 ----
  ISSUE(st0, 0)
  ISSUE(st1, 1)
  const float4 mv0 = *(const float4*)(mean + (size_t)d2 * Mm + m0 + mq * 4);
  const float4 mv1 =
      *(const float4*)(mean + (size_t)(d2 + 1) * Mm + m0 + mq * 4);

  short8 A[4][2];
#pragma unroll
  for (int ct = 0; ct < 4; ++ct) {
#pragma unroll
    for (int ks = 0; ks < 2; ++ks) {
      const float* sp = S + ((size_t)(m0 + w) * Cc + ct * 16 + (l & 15)) * Cc +
                        ks * 32 + (l >> 4) * 8;
      const float4 f0 = *(const float4*)sp;
      const float4 f1 = *(const float4*)(sp + 4);
      short8 a;
      a[0] = (short)f2bf(f0.x); a[1] = (short)f2bf(f0.y);
      a[2] = (short)f2bf(f0.z); a[3] = (short)f2bf(f0.w);
      a[4] = (short)f2bf(f1.x); a[5] = (short)f2bf(f1.y);
      a[6] = (short)f2bf(f1.z); a[7] = (short)f2bf(f1.w);
      A[ct][ks] = a;
    }
  }
  STAGE(st0, xbuf0)
  BAR()

  // ---- main loop: fully unrolled, compile-time parity (rule #20) ----
#define ITER(T, STC, STN)                                                      \
  {                                                                            \
    const unsigned char* xr = ((T)&1) ? xbuf1 : xbuf0;                         \
    unsigned char* xw = ((T)&1) ? xbuf0 : xbuf1;                               \
    const short8 Bf0 =                                                         \
        *(const short8*)(xr + rowB * 128 + xsw(rowB, (l >> 4)) * 16);          \
    const short8 Bf1 =                                                         \
        *(const short8*)(xr + rowB * 128 + xsw(rowB, 4 + (l >> 4)) * 16);      \
    if ((T) + 2 < NB) ISSUE(STN, (T) + 2)                                      \
    f32x4 ac0 = {0.f, 0.f, 0.f, 0.f}, ac1 = {0.f, 0.f, 0.f, 0.f},              \
          ac2 = {0.f, 0.f, 0.f, 0.f}, ac3 = {0.f, 0.f, 0.f, 0.f};              \
    ac0 = __builtin_amdgcn_mfma_f32_16x16x32_bf16(A[0][0], Bf0, ac0, 0, 0, 0); \
    ac1 = __builtin_amdgcn_mfma_f32_16x16x32_bf16(A[1][0], Bf0, ac1, 0, 0, 0); \
    ac2 = __builtin_amdgcn_mfma_f32_16x16x32_bf16(A[2][0], Bf0, ac2, 0, 0, 0); \
    ac3 = __builtin_amdgcn_mfma_f32_16x16x32_bf16(A[3][0], Bf0, ac3, 0, 0, 0); \
    ac0 = __builtin_amdgcn_mfma_f32_16x16x32_bf16(A[0][1], Bf1, ac0, 0, 0, 0); \
    ac1 = __builtin_amdgcn_mfma_f32_16x16x32_bf16(A[1][1], Bf1, ac1, 0, 0, 0); \
    ac2 = __builtin_amdgcn_mfma_f32_16x16x32_bf16(A[2][1], Bf1, ac2, 0, 0, 0); \
    ac3 = __builtin_amdgcn_mfma_f32_16x16x32_bf16(A[3][1], Bf1, ac3, 0, 0, 0); \
    if ((T) + 1 < NB) STAGE(STC, xw)                                           \
    BAR()                                                                      \
    _Pragma("unroll") for (int r = 0; r < 4; ++r) {                            \
      ZW(0, r, ac0) ZW(1, r, ac1) ZW(2, r, ac2) ZW(3, r, ac3)                  \
    }                                                                          \
    BAR()                                                                      \
    _Pragma("unroll") for (int t2 = 0; t2 < 4; ++t2) {                         \
      const int row = t2 * 256 + rs;                                           \
      const int qd = mq ^ ((row >> 6) & 3);                                    \
      const float4 v = *(const float4*)(zl + row * ZR + qd * 4);               \
      *(float4*)(out + (size_t)((bg + (T)*BT + (row & 15)) * Cc +              \
                                (row >> 4)) * Mm + m0 + mq * 4) = v;           \
    }                                                                          \
  }

  ITER(0, st1, st0)
  ITER(1, st0, st1)
  ITER(2, st1, st0)
  ITER(3, st0, st1)
  ITER(4, st1, st0)
  ITER(5, st0, st1)
  ITER(6, st1, st0)
  ITER(7, st0, st1)

#undef ITER
#undef ZW
#undef BAR
#undef STAGE
#undef ISSUE
}

extern "C" void kernel_launch(void* const* d_in, const int* in_sizes, int n_in,
                              void* d_out, int out_size, void* d_ws,
                              size_t ws_size, hipStream_t stream) {
  const float* x = (const float*)d_in[0];
  const float* mean = (const float*)d_in[1];
  const float* S = (const float*)d_in[2];
  float* out = (float*)d_out;
  const int nblocks = (Mm / MT) * (Bb / (BT * NB));  // 32 * 8 = 256
  hipLaunchKernelGGL(zca_pipe, dim3(nblocks), dim3(1024), LDSB, stream, x,
                     mean, S, out);
}